// Round 17
// baseline (543.409 us; speedup 1.0000x reference)
//
#include <hip/hip_runtime.h>

#define N 768
#define D 128
#define NSQ (N*N)
#define EPS 1e-5f

typedef __bf16 bf16;
typedef __bf16 bf16x4 __attribute__((ext_vector_type(4)));
typedef __bf16 bf16x8 __attribute__((ext_vector_type(8)));
typedef float f32x4 __attribute__((ext_vector_type(4)));

__device__ __forceinline__ void gld16(const void* g, void* l) {
    __builtin_amdgcn_global_load_lds(
        (const __attribute__((address_space(1))) unsigned int*)g,
        (__attribute__((address_space(3))) unsigned int*)l, 16, 0, 0);
}

// raw barrier: lgkm drain (LDS visibility) WITHOUT the vmcnt(0) store/DMA drain
__device__ __forceinline__ void barrier_lds() {
    asm volatile("s_waitcnt lgkmcnt(0)" ::: "memory");
    __builtin_amdgcn_s_barrier();
    __builtin_amdgcn_sched_barrier(0);
}

// ---------------- K0a: convert weights fp32 -> bf16, LN/cn gamma folded -----
__global__ void k_convert_w(const float* __restrict__ lp, const float* __restrict__ lg,
                            const float* __restrict__ rp, const float* __restrict__ rg,
                            const float* __restrict__ op, const float* __restrict__ og,
                            const float* __restrict__ lnw, const float* __restrict__ cnw,
                            bf16* __restrict__ dst) {
    const float* srcs[6] = {lp, lg, rp, rg, op, og};
    int m = blockIdx.y;
    int i = blockIdx.x * 256 + threadIdx.x;   // 64 blocks x 256 = 16384
    float v = srcs[m][i];
    int k = i & 127;
    if (m < 4) v *= lnw[k];
    else if (m == 4) v *= cnw[k];
    dst[m * 16384 + i] = (bf16)v;
}

// ---------------- K0b: adjusted biases b' = b + W @ beta --------------------
__global__ void k_bias(const float* __restrict__ lp_w, const float* __restrict__ lg_w,
                       const float* __restrict__ rp_w, const float* __restrict__ rg_w,
                       const float* __restrict__ op_w,
                       const float* __restrict__ lp_b, const float* __restrict__ lg_b,
                       const float* __restrict__ rp_b, const float* __restrict__ rg_b,
                       const float* __restrict__ op_b,
                       const float* __restrict__ lnb, const float* __restrict__ cnb,
                       float* __restrict__ outb) {
    int m = blockIdx.x;       // 0..4
    int d = threadIdx.x;      // 0..127
    const float* W[5] = {lp_w, lg_w, rp_w, rg_w, op_w};
    const float* B[5] = {lp_b, lg_b, rp_b, rg_b, op_b};
    const float* beta = (m < 4) ? lnb : cnb;
    float s = B[m][d];
    for (int k = 0; k < 128; ++k) s += W[m][d * 128 + k] * beta[k];
    outb[m * 128 + d] = s;
}

// zt geometry: PADDED rows of 17 x 16B slots (272 B). Row r starts at bank
// slot (r*17)%16 -> consecutive rows rotate 4 banks; linear columns, no XOR.
#define ZROW 272

// ---------------- K1v8: fused LN + 4 GEMMs + gates, padded zt ---------------
__global__ __launch_bounds__(512, 2) void k_ln_gate2(
    const float* __restrict__ pair, const bf16* __restrict__ wbf,
    const float* __restrict__ badj,
    bf16* __restrict__ left_t, bf16* __restrict__ right_t)
{
    __shared__ char zt[2][64 * ZROW];   // 2 x 17 KB padded

    const int t = threadIdx.x;
    const int lane = t & 63, wid = t >> 6;
    const int side = wid >> 2, dq = wid & 3;
    const int lr = lane & 15, lh = lane >> 4;

    const bf16* wPsrc = wbf + (side ? 2 : 0) * 16384;
    const bf16* wGsrc = wbf + (side ? 3 : 1) * 16384;
    const float* bPp = badj + (side ? 2 : 0) * 128;
    const float* bGp = badj + (side ? 3 : 1) * 128;
    bf16* dst = side ? right_t : left_t;

    bf16x8 aP[4][2], aG[4][2];
    #pragma unroll
    for (int kk = 0; kk < 4; ++kk)
        #pragma unroll
        for (int m = 0; m < 2; ++m) {
            int rd = dq * 32 + m * 16 + lr;
            aP[kk][m] = *(const bf16x8*)(wPsrc + rd * 128 + (kk * 4 + lh) * 8);
            aG[kk][m] = *(const bf16x8*)(wGsrc + rd * 128 + (kk * 4 + lh) * 8);
        }
    float bP[2], bG[2];
    #pragma unroll
    for (int m = 0; m < 2; ++m) {
        bP[m] = bPp[dq * 32 + m * 16 + lr];
        bG[m] = bGp[dq * 32 + m * 16 + lr];
    }

    const int r8 = t >> 3, q = t & 7;

    const int bid = blockIdx.x, gstride = gridDim.x;
    const int NT = NSQ / 64;

    f32x4 p0, p1, p2, p3;

    auto ln_to = [&](int b) {
        float x[16];
        #pragma unroll
        for (int e = 0; e < 4; ++e) {
            x[e] = p0[e]; x[4 + e] = p1[e]; x[8 + e] = p2[e]; x[12 + e] = p3[e];
        }
        float s1 = 0.f, s2 = 0.f;
        #pragma unroll
        for (int j = 0; j < 16; ++j) { s1 += x[j]; s2 += x[j] * x[j]; }
        s1 += __shfl_xor(s1, 1); s2 += __shfl_xor(s2, 1);
        s1 += __shfl_xor(s1, 2); s2 += __shfl_xor(s2, 2);
        s1 += __shfl_xor(s1, 4); s2 += __shfl_xor(s2, 4);
        float mean = s1 * (1.f / 128.f);
        float rstd = rsqrtf(s2 * (1.f / 128.f) - mean * mean + EPS);
        bf16x8 pk0, pk1;
        #pragma unroll
        for (int e = 0; e < 4; ++e) {
            pk0[e]     = (bf16)((x[e]      - mean) * rstd);
            pk0[4 + e] = (bf16)((x[4 + e]  - mean) * rstd);
            pk1[e]     = (bf16)((x[8 + e]  - mean) * rstd);
            pk1[4 + e] = (bf16)((x[12 + e] - mean) * rstd);
        }
        char* zb = &zt[b][0];
        *(bf16x8*)(zb + r8 * ZROW + (q * 2) * 16)     = pk0;
        *(bf16x8*)(zb + r8 * ZROW + (q * 2 + 1) * 16) = pk1;
    };
    auto load_regs = [&](int tile) {
        const float* prow = pair + (size_t)(tile * 64 + r8) * 128 + q * 16;
        p0 = *(const f32x4*)(prow);
        p1 = *(const f32x4*)(prow + 4);
        p2 = *(const f32x4*)(prow + 8);
        p3 = *(const f32x4*)(prow + 12);
    };

    load_regs(bid);
    ln_to(0);
    if (bid + gstride < NT) load_regs(bid + gstride);
    barrier_lds();

    int buf = 0;
    for (int tile = bid; tile < NT; tile += gstride) {
        const int row0 = tile * 64;
        const int nt = tile + gstride;

        if (nt < NT) ln_to(buf ^ 1);
        if (nt + gstride < NT) load_regs(nt + gstride);

        f32x4 accP[2][4] = {};
        f32x4 accG[2][4] = {};
        const char* zb = &zt[buf][0];
        #pragma unroll
        for (int kk = 0; kk < 4; ++kk) {
            bf16x8 bz[4];
            #pragma unroll
            for (int n = 0; n < 4; ++n) {
                int rz = n * 16 + lr;
                bz[n] = *(const bf16x8*)(zb + rz * ZROW + (kk * 4 + lh) * 16);
            }
            #pragma unroll
            for (int m = 0; m < 2; ++m)
                #pragma unroll
                for (int n = 0; n < 4; ++n) {
                    accP[m][n] = __builtin_amdgcn_mfma_f32_16x16x32_bf16(bz[n], aP[kk][m], accP[m][n], 0, 0, 0);
                    accG[m][n] = __builtin_amdgcn_mfma_f32_16x16x32_bf16(bz[n], aG[kk][m], accG[m][n], 0, 0, 0);
                }
        }

        #pragma unroll
        for (int m = 0; m < 2; ++m) {
            const int d = dq * 32 + m * 16 + lr;
            bf16* drow = dst + (size_t)d * NSQ + row0 + lh * 4;
            #pragma unroll
            for (int n = 0; n < 4; ++n) {
                bf16x4 pk;
                #pragma unroll
                for (int reg = 0; reg < 4; ++reg) {
                    float g = accG[m][n][reg] + bG[m];
                    float p = accP[m][n][reg] + bP[m];
                    pk[reg] = (bf16)(p * (1.f / (1.f + __expf(-g))));
                }
                *(bf16x4*)(drow + n * 16) = pk;
            }
        }
        barrier_lds();
        buf ^= 1;
    }
}

// ---------------- K3v10: 256^2, counted-vmcnt, 2 phases per K-tile ----------
__global__ __launch_bounds__(512, 2) void k_tri(
    const bf16* __restrict__ left_t, const bf16* __restrict__ right_t, bf16* __restrict__ tri_t)
{
    __shared__ bf16 at[2][256 * 64];   // 2 x 32 KB
    __shared__ bf16 bt[2][256 * 64];   // 2 x 32 KB
    const int t = threadIdx.x;
    const int b = blockIdx.x;
    const int xcd = b & 7;
    const int s = b >> 3;              // 0..143
    const int d = xcd * 16 + s / 9;
    const int tile = s % 9;
    const int ti = tile / 3, tj = tile % 3;
    const bf16* A = left_t + (size_t)d * NSQ;
    const bf16* B = right_t + (size_t)d * NSQ;
    const int i0 = ti * 256, j0 = tj * 256;

    const int lane = t & 63, wid = t >> 6;
    const int wr = wid >> 2, wc = wid & 3;
    const int lr = lane & 15, lh = lane >> 4;

    const bf16* SRC = (wid < 4) ? A : B;
    const int srcbase = (wid < 4) ? i0 : j0;
    const int w4 = wid & 3;
    auto stage4 = [&](int bf, int kt, int half) {
        char* dstb = (wid < 4) ? (char*)at[bf] : (char*)bt[bf];
        #pragma unroll
        for (int i2 = 0; i2 < 4; ++i2) {
            int i = half * 4 + i2;
            int rl = w4 * 64 + i * 8 + (lane >> 3);
            int lc = (lane & 7) ^ (rl & 7);
            gld16(SRC + (size_t)(srcbase + rl) * 768 + kt * 64 + lc * 8,
                  dstb + rl * 128 + (lane & 7) * 16);
        }
    };

    f32x4 acc[8][4] = {};

    stage4(0, 0, 0);
    stage4(0, 0, 1);
    asm volatile("s_waitcnt vmcnt(0)" ::: "memory");
    __builtin_amdgcn_s_barrier();
    __builtin_amdgcn_sched_barrier(0);

    for (int kt = 0; kt < 12; ++kt) {
        const int bf = kt & 1;
        const char* ab = (const char*)at[bf];
        const char* bb = (const char*)bt[bf];
        #pragma unroll
        for (int kk = 0; kk < 2; ++kk) {
            if (kk == 0) {
                if (kt < 11) {
                    stage4(bf ^ 1, kt + 1, 0);
                    asm volatile("s_waitcnt vmcnt(4)" ::: "memory");
                } else {
                    asm volatile("s_waitcnt vmcnt(0)" ::: "memory");
                }
                __builtin_amdgcn_s_barrier();
                __builtin_amdgcn_sched_barrier(0);
            } else {
                if (kt < 11) stage4(bf ^ 1, kt + 1, 1);
            }
            bf16x8 bff[4], af[8];
            #pragma unroll
            for (int n = 0; n < 4; ++n) {
                int r = wc * 64 + n * 16 + lr;
                bff[n] = *(const bf16x8*)(bb + r * 128 + (((kk * 4 + lh)) ^ (r & 7)) * 16);
            }
            #pragma unroll
            for (int mi = 0; mi < 8; ++mi) {
                int r = wr * 128 + mi * 16 + lr;
                af[mi] = *(const bf16x8*)(ab + r * 128 + (((kk * 4 + lh)) ^ (r & 7)) * 16);
            }
            asm volatile("s_waitcnt lgkmcnt(0)" ::: "memory");
            __builtin_amdgcn_sched_barrier(0);
            __builtin_amdgcn_s_setprio(1);
            #pragma unroll
            for (int mi = 0; mi < 8; ++mi)
                #pragma unroll
                for (int n = 0; n < 4; ++n)
                    acc[mi][n] = __builtin_amdgcn_mfma_f32_16x16x32_bf16(
                        bff[n], af[mi], acc[mi][n], 0, 0, 0);
            __builtin_amdgcn_s_setprio(0);
        }
        __builtin_amdgcn_s_barrier();
        __builtin_amdgcn_sched_barrier(0);
    }

    bf16* C = tri_t + (size_t)d * NSQ;
    #pragma unroll
    for (int m = 0; m < 8; ++m) {
        const int ri = i0 + wr * 128 + m * 16 + lr;
        bf16* crow = C + (size_t)ri * 768 + j0 + wc * 64 + lh * 4;
        #pragma unroll
        for (int n = 0; n < 4; ++n) {
            bf16x4 pk;
            #pragma unroll
            for (int reg = 0; reg < 4; ++reg)
                pk[reg] = (bf16)acc[m][n][reg];
            *(bf16x4*)(crow + n * 16) = pk;
        }
    }
}

// ---------------- K4v3: LN over d (gamma/beta folded downstream) ------------
__global__ __launch_bounds__(256, 2) void k_cln(
    const bf16* __restrict__ tri_t, bf16* __restrict__ tri_ln)
{
    __shared__ bf16 tile[256 * 128];   // 64 KB raw values
    __shared__ float mrs[256][2];      // mean, rstd
    const int t = threadIdx.x;
    const size_t ij = (size_t)blockIdx.x * 256 + t;
    float s1 = 0.f, s2 = 0.f;
    for (int dc = 0; dc < 16; ++dc) {
        bf16x8 pk;
        #pragma unroll
        for (int e = 0; e < 8; ++e) {
            int dd = dc * 8 + e;
            bf16 raw = tri_t[(size_t)dd * NSQ + ij];
            float v = (float)raw;
            s1 += v; s2 += v * v;
            pk[e] = raw;
        }
        *(bf16x8*)((char*)tile + t * 256 + (dc ^ (t & 7)) * 16) = pk;
    }
    float mean = s1 * (1.f / 128.f);
    float rstd = rsqrtf(s2 * (1.f / 128.f) - mean * mean + EPS);
    mrs[t][0] = mean; mrs[t][1] = rstd;
    __syncthreads();
    const size_t ij0 = (size_t)blockIdx.x * 256;
    #pragma unroll
    for (int c = 0; c < 16; ++c) {
        int sl = c * 256 + t;
        int rl = sl >> 4, cp = sl & 15, cl = cp ^ (rl & 7);
        bf16x8 raw = *(const bf16x8*)((const char*)tile + rl * 256 + cp * 16);
        float m = mrs[rl][0], r = mrs[rl][1];
        bf16x8 o;
        #pragma unroll
        for (int e = 0; e < 8; ++e)
            o[e] = (bf16)(((float)raw[e] - m) * r);
        *(bf16x8*)(tri_ln + (ij0 + rl) * 128 + cl * 8) = o;
    }
}

// ---------------- K5v8: persistent fused out-gate + residual + final LN -----
// zt/ub register-written -> padded 272B rows (conflict-free); tt is DMA'd so
// keeps linear-256B + XOR swizzle.
__global__ __launch_bounds__(512, 2) void k_final2(
    const float* __restrict__ pair, const bf16* __restrict__ tri_ln,
    const bf16* __restrict__ wbf,
    const float* __restrict__ opb_adj, const float* __restrict__ og_b,
    const float* __restrict__ lnow, const float* __restrict__ lnob,
    float* __restrict__ out)
{
    __shared__ char zt[64 * ZROW];      // raw pair bf16, padded       17 KB
    __shared__ bf16 tt[2][64 * 128];    // tri_ln, swizzled, dbuf      32 KB
    __shared__ bf16 ub[64 * 136];       // gated output exchange       17 KB

    const int t = threadIdx.x;
    const int lane = t & 63, wid = t >> 6;
    const int dq = wid & 3, wh = wid >> 2;
    const int lr = lane & 15, lh = lane >> 4;

    const bf16* opsrc = wbf + 4 * 16384;
    const bf16* ogsrc = wbf + 5 * 16384;

    bf16x8 aOG[4][2], aOP[4][2];
    #pragma unroll
    for (int kk = 0; kk < 4; ++kk)
        #pragma unroll
        for (int m = 0; m < 2; ++m) {
            int rd = dq * 32 + m * 16 + lr;
            aOG[kk][m] = *(const bf16x8*)(ogsrc + rd * 128 + (kk * 4 + lh) * 8);
            aOP[kk][m] = *(const bf16x8*)(opsrc + rd * 128 + (kk * 4 + lh) * 8);
        }
    f32x4 vbOG[2], vbOP[2];
    #pragma unroll
    for (int m = 0; m < 2; ++m) {
        vbOG[m] = *(const f32x4*)(og_b + dq * 32 + m * 16 + lh * 4);
        vbOP[m] = *(const f32x4*)(opb_adj + dq * 32 + m * 16 + lh * 4);
    }

    const int r8 = t >> 3, q = t & 7;
    f32x4 lw0 = *(const f32x4*)(lnow + q * 16);
    f32x4 lw1 = *(const f32x4*)(lnow + q * 16 + 4);
    f32x4 lw2 = *(const f32x4*)(lnow + q * 16 + 8);
    f32x4 lw3 = *(const f32x4*)(lnow + q * 16 + 12);
    f32x4 lb0 = *(const f32x4*)(lnob + q * 16);
    f32x4 lb1 = *(const f32x4*)(lnob + q * 16 + 4);
    f32x4 lb2 = *(const f32x4*)(lnob + q * 16 + 8);
    f32x4 lb3 = *(const f32x4*)(lnob + q * 16 + 12);

    const int bid = blockIdx.x, gstride = gridDim.x;

    auto stage_tt = [&](int buf, int tile) {
        const int row0 = tile * 64;
        #pragma unroll
        for (int c = 0; c < 2; ++c) {
            int s = c * 512 + t;                 // 1024 slots of 16B
            int r = s >> 4, cp = s & 15, cl = cp ^ (r & 7);
            gld16(tri_ln + (size_t)(row0 + r) * 128 + cl * 8, (char*)tt[buf] + s * 16);
        }
    };

    stage_tt(0, bid);
    f32x4 pA0, pA1, pA2, pA3;
    {
        const float* prow = pair + (size_t)(bid * 64 + r8) * 128 + q * 16;
        pA0 = *(const f32x4*)(prow);
        pA1 = *(const f32x4*)(prow + 4);
        pA2 = *(const f32x4*)(prow + 8);
        pA3 = *(const f32x4*)(prow + 12);
    }

    int buf = 0;
    for (int tile = bid; tile < NSQ / 64; tile += gstride) {
        const int row0 = tile * 64;

        {
            bf16x8 pk0, pk1;
            #pragma unroll
            for (int e = 0; e < 4; ++e) {
                pk0[e]     = (bf16)pA0[e];
                pk0[4 + e] = (bf16)pA1[e];
                pk1[e]     = (bf16)pA2[e];
                pk1[4 + e] = (bf16)pA3[e];
            }
            *(bf16x8*)(zt + r8 * ZROW + (q * 2) * 16)     = pk0;
            *(bf16x8*)(zt + r8 * ZROW + (q * 2 + 1) * 16) = pk1;
        }
        barrier_lds();   // A: zt + tt[buf] ready

        const int nt = tile + gstride;
        if (nt < NSQ / 64) stage_tt(buf ^ 1, nt);

        f32x4 pB0 = pA0, pB1 = pA1, pB2 = pA2, pB3 = pA3;
        if (nt < NSQ / 64) {
            const float* prow = pair + (size_t)(nt * 64 + r8) * 128 + q * 16;
            pB0 = *(const f32x4*)(prow);
            pB1 = *(const f32x4*)(prow + 4);
            pB2 = *(const f32x4*)(prow + 8);
            pB3 = *(const f32x4*)(prow + 12);
        }

        f32x4 accOG[2][2] = {};
        f32x4 accOP[2][2] = {};
        const char* tb = (const char*)tt[buf];
        #pragma unroll
        for (int kk = 0; kk < 4; ++kk) {
            bf16x8 bzp[2], bzt[2];
            #pragma unroll
            for (int n = 0; n < 2; ++n) {
                int rz = wh * 32 + n * 16 + lr;
                bzp[n] = *(const bf16x8*)(zt + rz * ZROW + (kk * 4 + lh) * 16);
                bzt[n] = *(const bf16x8*)(tb + rz * 256 + (((kk * 4 + lh)) ^ (rz & 7)) * 16);
            }
            #pragma unroll
            for (int m = 0; m < 2; ++m)
                #pragma unroll
                for (int n = 0; n < 2; ++n) {
                    accOG[m][n] = __builtin_amdgcn_mfma_f32_16x16x32_bf16(aOG[kk][m], bzp[n], accOG[m][n], 0, 0, 0);
                    accOP[m][n] = __builtin_amdgcn_mfma_f32_16x16x32_bf16(aOP[kk][m], bzt[n], accOP[m][n], 0, 0, 0);
                }
        }

        #pragma unroll
        for (int m = 0; m < 2; ++m)
            #pragma unroll
            for (int n = 0; n < 2; ++n) {
                int rr = wh * 32 + n * 16 + lr;
                bf16x4 v;
                #pragma unroll
                for (int reg = 0; reg < 4; ++reg) {
                    float g = accOG[m][n][reg] + vbOG[m][reg];
                    float p = accOP[m][n][reg] + vbOP[m][reg];
                    v[reg] = (bf16)(p * (1.f / (1.f + __expf(-g))));
                }
                *(bf16x4*)(ub + rr * 136 + dq * 32 + m * 16 + lh * 4) = v;
            }
        barrier_lds();   // B: ub visible; no vmcnt drain

        {
            float x[16];
            const bf16* ur = ub + r8 * 136 + q * 16;
            bf16x8 u0 = *(const bf16x8*)(ur);
            bf16x8 u1 = *(const bf16x8*)(ur + 8);
            #pragma unroll
            for (int e = 0; e < 4; ++e) {
                x[e]      = pA0[e] + (float)u0[e];
                x[4 + e]  = pA1[e] + (float)u0[4 + e];
                x[8 + e]  = pA2[e] + (float)u1[e];
                x[12 + e] = pA3[e] + (float)u1[4 + e];
            }
            float s1 = 0.f, s2 = 0.f;
            #pragma unroll
            for (int j = 0; j < 16; ++j) { s1 += x[j]; s2 += x[j] * x[j]; }
            s1 += __shfl_xor(s1, 1); s2 += __shfl_xor(s2, 1);
            s1 += __shfl_xor(s1, 2); s2 += __shfl_xor(s2, 2);
            s1 += __shfl_xor(s1, 4); s2 += __shfl_xor(s2, 4);
            float mean = s1 * (1.f / 128.f);
            float rstd = rsqrtf(s2 * (1.f / 128.f) - mean * mean + EPS);
            float* orow = out + (size_t)(row0 + r8) * 128 + q * 16;
            f32x4 o0, o1, o2, o3;
            #pragma unroll
            for (int e = 0; e < 4; ++e) {
                o0[e] = (x[e]      - mean) * rstd * lw0[e] + lb0[e];
                o1[e] = (x[4 + e]  - mean) * rstd * lw1[e] + lb1[e];
                o2[e] = (x[8 + e]  - mean) * rstd * lw2[e] + lb2[e];
                o3[e] = (x[12 + e] - mean) * rstd * lw3[e] + lb3[e];
            }
            *(f32x4*)(orow)      = o0;
            *(f32x4*)(orow + 4)  = o1;
            *(f32x4*)(orow + 8)  = o2;
            *(f32x4*)(orow + 12) = o3;
        }

        pA0 = pB0; pA1 = pB1; pA2 = pB2; pA3 = pB3;
        buf ^= 1;
    }
}

extern "C" void kernel_launch(void* const* d_in, const int* in_sizes, int n_in,
                              void* d_out, int out_size, void* d_ws, size_t ws_size,
                              hipStream_t stream) {
    const float* pair    = (const float*)d_in[0];
    const float* ln_in_w = (const float*)d_in[1];
    const float* ln_in_b = (const float*)d_in[2];
    const float* lp_w    = (const float*)d_in[3];
    const float* lp_b    = (const float*)d_in[4];
    const float* lg_w    = (const float*)d_in[5];
    const float* lg_b    = (const float*)d_in[6];
    const float* rp_w    = (const float*)d_in[7];
    const float* rp_b    = (const float*)d_in[8];
    const float* rg_w    = (const float*)d_in[9];
    const float* rg_b    = (const float*)d_in[10];
    const float* cn_w    = (const float*)d_in[11];
    const float* cn_b    = (const float*)d_in[12];
    const float* op_w    = (const float*)d_in[13];
    const float* op_b    = (const float*)d_in[14];
    const float* og_w    = (const float*)d_in[15];
    const float* og_b    = (const float*)d_in[16];
    const float* ln_out_w = (const float*)d_in[17];
    const float* ln_out_b = (const float*)d_in[18];

    const size_t HALF = (size_t)128 * NSQ * 2;   // 150,994,944 B
    char* ws = (char*)d_ws;
    bf16*  wbf     = (bf16*)ws;                   // 196608 B
    float* badj    = (float*)(ws + 196608);       // 5 x 128 fp32
    bf16*  right_t = (bf16*)(ws + 196608 + 4096);
    bf16*  tri_ln  = right_t;                     // reuse after K3
    bf16*  left_t  = (bf16*)d_out;
    bf16*  tri_t   = (bf16*)((char*)d_out + HALF);

    k_convert_w<<<dim3(64, 6), 256, 0, stream>>>(lp_w, lg_w, rp_w, rg_w, op_w, og_w,
                                                 ln_in_w, cn_w, wbf);
    k_bias<<<dim3(5), 128, 0, stream>>>(lp_w, lg_w, rp_w, rg_w, op_w,
                                        lp_b, lg_b, rp_b, rg_b, op_b,
                                        ln_in_b, cn_b, badj);
    k_ln_gate2<<<dim3(768), 512, 0, stream>>>(pair, wbf, badj, left_t, right_t);
    k_tri<<<dim3(1152), 512, 0, stream>>>(left_t, right_t, tri_t);
    k_cln<<<dim3(NSQ / 256), 256, 0, stream>>>(tri_t, tri_ln);
    k_final2<<<dim3(512), 512, 0, stream>>>(pair, tri_ln, wbf, badj + 512, og_b,
                                            ln_out_w, ln_out_b, (float*)d_out);
}

// Round 18
// 525.582 us; speedup vs baseline: 1.0339x; 1.0339x over previous
//
#include <hip/hip_runtime.h>

#define N 768
#define D 128
#define NSQ (N*N)
#define EPS 1e-5f

typedef __bf16 bf16;
typedef __bf16 bf16x4 __attribute__((ext_vector_type(4)));
typedef __bf16 bf16x8 __attribute__((ext_vector_type(8)));
typedef float f32x4 __attribute__((ext_vector_type(4)));

__device__ __forceinline__ void gld16(const void* g, void* l) {
    __builtin_amdgcn_global_load_lds(
        (const __attribute__((address_space(1))) unsigned int*)g,
        (__attribute__((address_space(3))) unsigned int*)l, 16, 0, 0);
}

// raw barrier: lgkm drain (LDS visibility) WITHOUT the vmcnt(0) store/DMA drain
__device__ __forceinline__ void barrier_lds() {
    asm volatile("s_waitcnt lgkmcnt(0)" ::: "memory");
    __builtin_amdgcn_s_barrier();
    __builtin_amdgcn_sched_barrier(0);
}

// ---------------- K0a: convert weights fp32 -> bf16, LN/cn gamma folded -----
__global__ void k_convert_w(const float* __restrict__ lp, const float* __restrict__ lg,
                            const float* __restrict__ rp, const float* __restrict__ rg,
                            const float* __restrict__ op, const float* __restrict__ og,
                            const float* __restrict__ lnw, const float* __restrict__ cnw,
                            bf16* __restrict__ dst) {
    const float* srcs[6] = {lp, lg, rp, rg, op, og};
    int m = blockIdx.y;
    int i = blockIdx.x * 256 + threadIdx.x;   // 64 blocks x 256 = 16384
    float v = srcs[m][i];
    int k = i & 127;
    if (m < 4) v *= lnw[k];
    else if (m == 4) v *= cnw[k];
    dst[m * 16384 + i] = (bf16)v;
}

// ---------------- K0b: adjusted biases b' = b + W @ beta --------------------
__global__ void k_bias(const float* __restrict__ lp_w, const float* __restrict__ lg_w,
                       const float* __restrict__ rp_w, const float* __restrict__ rg_w,
                       const float* __restrict__ op_w,
                       const float* __restrict__ lp_b, const float* __restrict__ lg_b,
                       const float* __restrict__ rp_b, const float* __restrict__ rg_b,
                       const float* __restrict__ op_b,
                       const float* __restrict__ lnb, const float* __restrict__ cnb,
                       float* __restrict__ outb) {
    int m = blockIdx.x;       // 0..4
    int d = threadIdx.x;      // 0..127
    const float* W[5] = {lp_w, lg_w, rp_w, rg_w, op_w};
    const float* B[5] = {lp_b, lg_b, rp_b, rg_b, op_b};
    const float* beta = (m < 4) ? lnb : cnb;
    float s = B[m][d];
    for (int k = 0; k < 128; ++k) s += W[m][d * 128 + k] * beta[k];
    outb[m * 128 + d] = s;
}

// ---------------- K1v9: fused LN + 4 GEMMs + gates, bias-in-acc -------------
// Bias folded into MFMA C-in (acc col = d = lr is lane-constant -> splat).
// NOTE: SQ_LDS_BANK_CONFLICT is layout-invariant here (b128 multi-cycle
// artifact) -- XOR swizzle retained, padding reverted (R17 neutral).
__global__ __launch_bounds__(512, 2) void k_ln_gate2(
    const float* __restrict__ pair, const bf16* __restrict__ wbf,
    const float* __restrict__ badj,
    bf16* __restrict__ left_t, bf16* __restrict__ right_t)
{
    __shared__ bf16 zt[2][64 * 128];   // 2 x 16 KB, xor-swizzled 16B chunks

    const int t = threadIdx.x;
    const int lane = t & 63, wid = t >> 6;
    const int side = wid >> 2, dq = wid & 3;
    const int lr = lane & 15, lh = lane >> 4;

    const bf16* wPsrc = wbf + (side ? 2 : 0) * 16384;
    const bf16* wGsrc = wbf + (side ? 3 : 1) * 16384;
    const float* bPp = badj + (side ? 2 : 0) * 128;
    const float* bGp = badj + (side ? 3 : 1) * 128;
    bf16* dst = side ? right_t : left_t;

    bf16x8 aP[4][2], aG[4][2];
    #pragma unroll
    for (int kk = 0; kk < 4; ++kk)
        #pragma unroll
        for (int m = 0; m < 2; ++m) {
            int rd = dq * 32 + m * 16 + lr;
            aP[kk][m] = *(const bf16x8*)(wPsrc + rd * 128 + (kk * 4 + lh) * 8);
            aG[kk][m] = *(const bf16x8*)(wGsrc + rd * 128 + (kk * 4 + lh) * 8);
        }
    float bP[2], bG[2];
    #pragma unroll
    for (int m = 0; m < 2; ++m) {
        bP[m] = bPp[dq * 32 + m * 16 + lr];
        bG[m] = bGp[dq * 32 + m * 16 + lr];
    }

    const int r8 = t >> 3, q = t & 7;

    const int bid = blockIdx.x, gstride = gridDim.x;
    const int NT = NSQ / 64;

    f32x4 p0, p1, p2, p3;

    auto ln_to = [&](int b) {
        float x[16];
        #pragma unroll
        for (int e = 0; e < 4; ++e) {
            x[e] = p0[e]; x[4 + e] = p1[e]; x[8 + e] = p2[e]; x[12 + e] = p3[e];
        }
        float s1 = 0.f, s2 = 0.f;
        #pragma unroll
        for (int j = 0; j < 16; ++j) { s1 += x[j]; s2 += x[j] * x[j]; }
        s1 += __shfl_xor(s1, 1); s2 += __shfl_xor(s2, 1);
        s1 += __shfl_xor(s1, 2); s2 += __shfl_xor(s2, 2);
        s1 += __shfl_xor(s1, 4); s2 += __shfl_xor(s2, 4);
        float mean = s1 * (1.f / 128.f);
        float rstd = rsqrtf(s2 * (1.f / 128.f) - mean * mean + EPS);
        bf16x8 pk0, pk1;
        #pragma unroll
        for (int e = 0; e < 4; ++e) {
            pk0[e]     = (bf16)((x[e]      - mean) * rstd);
            pk0[4 + e] = (bf16)((x[4 + e]  - mean) * rstd);
            pk1[e]     = (bf16)((x[8 + e]  - mean) * rstd);
            pk1[4 + e] = (bf16)((x[12 + e] - mean) * rstd);
        }
        char* zb = (char*)&zt[b][0];
        *(bf16x8*)(zb + r8 * 256 + ((q * 2)     ^ (r8 & 7)) * 16) = pk0;
        *(bf16x8*)(zb + r8 * 256 + ((q * 2 + 1) ^ (r8 & 7)) * 16) = pk1;
    };
    auto load_regs = [&](int tile) {
        const float* prow = pair + (size_t)(tile * 64 + r8) * 128 + q * 16;
        p0 = *(const f32x4*)(prow);
        p1 = *(const f32x4*)(prow + 4);
        p2 = *(const f32x4*)(prow + 8);
        p3 = *(const f32x4*)(prow + 12);
    };

    load_regs(bid);
    ln_to(0);
    if (bid + gstride < NT) load_regs(bid + gstride);
    barrier_lds();

    int buf = 0;
    for (int tile = bid; tile < NT; tile += gstride) {
        const int row0 = tile * 64;
        const int nt = tile + gstride;

        if (nt < NT) ln_to(buf ^ 1);
        if (nt + gstride < NT) load_regs(nt + gstride);

        // bias pre-loaded into accumulators (C-in accumulates)
        f32x4 accP[2][4], accG[2][4];
        #pragma unroll
        for (int m = 0; m < 2; ++m)
            #pragma unroll
            for (int n = 0; n < 4; ++n) {
                accP[m][n] = f32x4{bP[m], bP[m], bP[m], bP[m]};
                accG[m][n] = f32x4{bG[m], bG[m], bG[m], bG[m]};
            }
        const char* zb = (const char*)&zt[buf][0];
        #pragma unroll
        for (int kk = 0; kk < 4; ++kk) {
            bf16x8 bz[4];
            #pragma unroll
            for (int n = 0; n < 4; ++n) {
                int rz = n * 16 + lr;
                bz[n] = *(const bf16x8*)(zb + rz * 256 + (((kk * 4 + lh)) ^ (rz & 7)) * 16);
            }
            #pragma unroll
            for (int m = 0; m < 2; ++m)
                #pragma unroll
                for (int n = 0; n < 4; ++n) {
                    accP[m][n] = __builtin_amdgcn_mfma_f32_16x16x32_bf16(bz[n], aP[kk][m], accP[m][n], 0, 0, 0);
                    accG[m][n] = __builtin_amdgcn_mfma_f32_16x16x32_bf16(bz[n], aG[kk][m], accG[m][n], 0, 0, 0);
                }
        }

        #pragma unroll
        for (int m = 0; m < 2; ++m) {
            const int d = dq * 32 + m * 16 + lr;
            bf16* drow = dst + (size_t)d * NSQ + row0 + lh * 4;
            #pragma unroll
            for (int n = 0; n < 4; ++n) {
                bf16x4 pk;
                #pragma unroll
                for (int reg = 0; reg < 4; ++reg) {
                    float g = accG[m][n][reg];
                    float p = accP[m][n][reg];
                    pk[reg] = (bf16)(p * (1.f / (1.f + __expf(-g))));
                }
                *(bf16x4*)(drow + n * 16) = pk;
            }
        }
        barrier_lds();
        buf ^= 1;
    }
}

// ---------------- K3v10: 256^2, counted-vmcnt, 2 phases per K-tile ----------
__global__ __launch_bounds__(512, 2) void k_tri(
    const bf16* __restrict__ left_t, const bf16* __restrict__ right_t, bf16* __restrict__ tri_t)
{
    __shared__ bf16 at[2][256 * 64];   // 2 x 32 KB
    __shared__ bf16 bt[2][256 * 64];   // 2 x 32 KB
    const int t = threadIdx.x;
    const int b = blockIdx.x;
    const int xcd = b & 7;
    const int s = b >> 3;              // 0..143
    const int d = xcd * 16 + s / 9;
    const int tile = s % 9;
    const int ti = tile / 3, tj = tile % 3;
    const bf16* A = left_t + (size_t)d * NSQ;
    const bf16* B = right_t + (size_t)d * NSQ;
    const int i0 = ti * 256, j0 = tj * 256;

    const int lane = t & 63, wid = t >> 6;
    const int wr = wid >> 2, wc = wid & 3;
    const int lr = lane & 15, lh = lane >> 4;

    const bf16* SRC = (wid < 4) ? A : B;
    const int srcbase = (wid < 4) ? i0 : j0;
    const int w4 = wid & 3;
    auto stage4 = [&](int bf, int kt, int half) {
        char* dstb = (wid < 4) ? (char*)at[bf] : (char*)bt[bf];
        #pragma unroll
        for (int i2 = 0; i2 < 4; ++i2) {
            int i = half * 4 + i2;
            int rl = w4 * 64 + i * 8 + (lane >> 3);
            int lc = (lane & 7) ^ (rl & 7);
            gld16(SRC + (size_t)(srcbase + rl) * 768 + kt * 64 + lc * 8,
                  dstb + rl * 128 + (lane & 7) * 16);
        }
    };

    f32x4 acc[8][4] = {};

    stage4(0, 0, 0);
    stage4(0, 0, 1);
    asm volatile("s_waitcnt vmcnt(0)" ::: "memory");
    __builtin_amdgcn_s_barrier();
    __builtin_amdgcn_sched_barrier(0);

    for (int kt = 0; kt < 12; ++kt) {
        const int bf = kt & 1;
        const char* ab = (const char*)at[bf];
        const char* bb = (const char*)bt[bf];
        #pragma unroll
        for (int kk = 0; kk < 2; ++kk) {
            if (kk == 0) {
                if (kt < 11) {
                    stage4(bf ^ 1, kt + 1, 0);
                    asm volatile("s_waitcnt vmcnt(4)" ::: "memory");
                } else {
                    asm volatile("s_waitcnt vmcnt(0)" ::: "memory");
                }
                __builtin_amdgcn_s_barrier();
                __builtin_amdgcn_sched_barrier(0);
            } else {
                if (kt < 11) stage4(bf ^ 1, kt + 1, 1);
            }
            bf16x8 bff[4], af[8];
            #pragma unroll
            for (int n = 0; n < 4; ++n) {
                int r = wc * 64 + n * 16 + lr;
                bff[n] = *(const bf16x8*)(bb + r * 128 + (((kk * 4 + lh)) ^ (r & 7)) * 16);
            }
            #pragma unroll
            for (int mi = 0; mi < 8; ++mi) {
                int r = wr * 128 + mi * 16 + lr;
                af[mi] = *(const bf16x8*)(ab + r * 128 + (((kk * 4 + lh)) ^ (r & 7)) * 16);
            }
            asm volatile("s_waitcnt lgkmcnt(0)" ::: "memory");
            __builtin_amdgcn_sched_barrier(0);
            __builtin_amdgcn_s_setprio(1);
            #pragma unroll
            for (int mi = 0; mi < 8; ++mi)
                #pragma unroll
                for (int n = 0; n < 4; ++n)
                    acc[mi][n] = __builtin_amdgcn_mfma_f32_16x16x32_bf16(
                        bff[n], af[mi], acc[mi][n], 0, 0, 0);
            __builtin_amdgcn_s_setprio(0);
        }
        __builtin_amdgcn_s_barrier();
        __builtin_amdgcn_sched_barrier(0);
    }

    bf16* C = tri_t + (size_t)d * NSQ;
    #pragma unroll
    for (int m = 0; m < 8; ++m) {
        const int ri = i0 + wr * 128 + m * 16 + lr;
        bf16* crow = C + (size_t)ri * 768 + j0 + wc * 64 + lh * 4;
        #pragma unroll
        for (int n = 0; n < 4; ++n) {
            bf16x4 pk;
            #pragma unroll
            for (int reg = 0; reg < 4; ++reg)
                pk[reg] = (bf16)acc[m][n][reg];
            *(bf16x4*)(crow + n * 16) = pk;
        }
    }
}

// ---------------- K4v3: LN over d (gamma/beta folded downstream) ------------
__global__ __launch_bounds__(256, 2) void k_cln(
    const bf16* __restrict__ tri_t, bf16* __restrict__ tri_ln)
{
    __shared__ bf16 tile[256 * 128];   // 64 KB raw values
    __shared__ float mrs[256][2];      // mean, rstd
    const int t = threadIdx.x;
    const size_t ij = (size_t)blockIdx.x * 256 + t;
    float s1 = 0.f, s2 = 0.f;
    for (int dc = 0; dc < 16; ++dc) {
        bf16x8 pk;
        #pragma unroll
        for (int e = 0; e < 8; ++e) {
            int dd = dc * 8 + e;
            bf16 raw = tri_t[(size_t)dd * NSQ + ij];
            float v = (float)raw;
            s1 += v; s2 += v * v;
            pk[e] = raw;
        }
        *(bf16x8*)((char*)tile + t * 256 + (dc ^ (t & 7)) * 16) = pk;
    }
    float mean = s1 * (1.f / 128.f);
    float rstd = rsqrtf(s2 * (1.f / 128.f) - mean * mean + EPS);
    mrs[t][0] = mean; mrs[t][1] = rstd;
    __syncthreads();
    const size_t ij0 = (size_t)blockIdx.x * 256;
    #pragma unroll
    for (int c = 0; c < 16; ++c) {
        int sl = c * 256 + t;
        int rl = sl >> 4, cp = sl & 15, cl = cp ^ (rl & 7);
        bf16x8 raw = *(const bf16x8*)((const char*)tile + rl * 256 + cp * 16);
        float m = mrs[rl][0], r = mrs[rl][1];
        bf16x8 o;
        #pragma unroll
        for (int e = 0; e < 8; ++e)
            o[e] = (bf16)(((float)raw[e] - m) * r);
        *(bf16x8*)(tri_ln + (ij0 + rl) * 128 + cl * 8) = o;
    }
}

// ---------------- K5v9: fused out-gate + residual + final LN, bias-in-acc ---
__global__ __launch_bounds__(512, 2) void k_final2(
    const float* __restrict__ pair, const bf16* __restrict__ tri_ln,
    const bf16* __restrict__ wbf,
    const float* __restrict__ opb_adj, const float* __restrict__ og_b,
    const float* __restrict__ lnow, const float* __restrict__ lnob,
    float* __restrict__ out)
{
    __shared__ bf16 zt[64 * 128];       // raw pair bf16, swizzled      16 KB
    __shared__ bf16 tt[2][64 * 128];    // tri_ln, swizzled, dbuf       32 KB
    __shared__ bf16 ub[64 * 136];       // gated output exchange        17 KB

    const int t = threadIdx.x;
    const int lane = t & 63, wid = t >> 6;
    const int dq = wid & 3, wh = wid >> 2;
    const int lr = lane & 15, lh = lane >> 4;

    const bf16* opsrc = wbf + 4 * 16384;
    const bf16* ogsrc = wbf + 5 * 16384;

    bf16x8 aOG[4][2], aOP[4][2];
    #pragma unroll
    for (int kk = 0; kk < 4; ++kk)
        #pragma unroll
        for (int m = 0; m < 2; ++m) {
            int rd = dq * 32 + m * 16 + lr;
            aOG[kk][m] = *(const bf16x8*)(ogsrc + rd * 128 + (kk * 4 + lh) * 8);
            aOP[kk][m] = *(const bf16x8*)(opsrc + rd * 128 + (kk * 4 + lh) * 8);
        }
    f32x4 vbOG[2], vbOP[2];
    #pragma unroll
    for (int m = 0; m < 2; ++m) {
        vbOG[m] = *(const f32x4*)(og_b + dq * 32 + m * 16 + lh * 4);
        vbOP[m] = *(const f32x4*)(opb_adj + dq * 32 + m * 16 + lh * 4);
    }

    const int r8 = t >> 3, q = t & 7;
    f32x4 lw0 = *(const f32x4*)(lnow + q * 16);
    f32x4 lw1 = *(const f32x4*)(lnow + q * 16 + 4);
    f32x4 lw2 = *(const f32x4*)(lnow + q * 16 + 8);
    f32x4 lw3 = *(const f32x4*)(lnow + q * 16 + 12);
    f32x4 lb0 = *(const f32x4*)(lnob + q * 16);
    f32x4 lb1 = *(const f32x4*)(lnob + q * 16 + 4);
    f32x4 lb2 = *(const f32x4*)(lnob + q * 16 + 8);
    f32x4 lb3 = *(const f32x4*)(lnob + q * 16 + 12);

    const int bid = blockIdx.x, gstride = gridDim.x;

    auto stage_tt = [&](int buf, int tile) {
        const int row0 = tile * 64;
        #pragma unroll
        for (int c = 0; c < 2; ++c) {
            int s = c * 512 + t;                 // 1024 slots of 16B
            int r = s >> 4, cp = s & 15, cl = cp ^ (r & 7);
            gld16(tri_ln + (size_t)(row0 + r) * 128 + cl * 8, (char*)tt[buf] + s * 16);
        }
    };

    stage_tt(0, bid);
    f32x4 pA0, pA1, pA2, pA3;
    {
        const float* prow = pair + (size_t)(bid * 64 + r8) * 128 + q * 16;
        pA0 = *(const f32x4*)(prow);
        pA1 = *(const f32x4*)(prow + 4);
        pA2 = *(const f32x4*)(prow + 8);
        pA3 = *(const f32x4*)(prow + 12);
    }

    int buf = 0;
    for (int tile = bid; tile < NSQ / 64; tile += gstride) {
        const int row0 = tile * 64;

        {
            bf16x8 pk0, pk1;
            #pragma unroll
            for (int e = 0; e < 4; ++e) {
                pk0[e]     = (bf16)pA0[e];
                pk0[4 + e] = (bf16)pA1[e];
                pk1[e]     = (bf16)pA2[e];
                pk1[4 + e] = (bf16)pA3[e];
            }
            char* zb = (char*)zt;
            *(bf16x8*)(zb + r8 * 256 + ((q * 2)     ^ (r8 & 7)) * 16) = pk0;
            *(bf16x8*)(zb + r8 * 256 + ((q * 2 + 1) ^ (r8 & 7)) * 16) = pk1;
        }
        barrier_lds();   // A: zt + tt[buf] ready

        const int nt = tile + gstride;
        if (nt < NSQ / 64) stage_tt(buf ^ 1, nt);

        f32x4 pB0 = pA0, pB1 = pA1, pB2 = pA2, pB3 = pA3;
        if (nt < NSQ / 64) {
            const float* prow = pair + (size_t)(nt * 64 + r8) * 128 + q * 16;
            pB0 = *(const f32x4*)(prow);
            pB1 = *(const f32x4*)(prow + 4);
            pB2 = *(const f32x4*)(prow + 8);
            pB3 = *(const f32x4*)(prow + 12);
        }

        // bias pre-loaded into accumulators (acc row = d = lh*4+reg -> f32x4)
        f32x4 accOG[2][2], accOP[2][2];
        #pragma unroll
        for (int m = 0; m < 2; ++m)
            #pragma unroll
            for (int n = 0; n < 2; ++n) {
                accOG[m][n] = vbOG[m];
                accOP[m][n] = vbOP[m];
            }
        const char* zb = (const char*)zt;
        const char* tb = (const char*)tt[buf];
        #pragma unroll
        for (int kk = 0; kk < 4; ++kk) {
            bf16x8 bzp[2], bzt[2];
            #pragma unroll
            for (int n = 0; n < 2; ++n) {
                int rz = wh * 32 + n * 16 + lr;
                int phys = (kk * 4 + lh) ^ (rz & 7);
                bzp[n] = *(const bf16x8*)(zb + rz * 256 + phys * 16);
                bzt[n] = *(const bf16x8*)(tb + rz * 256 + phys * 16);
            }
            #pragma unroll
            for (int m = 0; m < 2; ++m)
                #pragma unroll
                for (int n = 0; n < 2; ++n) {
                    accOG[m][n] = __builtin_amdgcn_mfma_f32_16x16x32_bf16(aOG[kk][m], bzp[n], accOG[m][n], 0, 0, 0);
                    accOP[m][n] = __builtin_amdgcn_mfma_f32_16x16x32_bf16(aOP[kk][m], bzt[n], accOP[m][n], 0, 0, 0);
                }
        }

        #pragma unroll
        for (int m = 0; m < 2; ++m)
            #pragma unroll
            for (int n = 0; n < 2; ++n) {
                int rr = wh * 32 + n * 16 + lr;
                bf16x4 v;
                #pragma unroll
                for (int reg = 0; reg < 4; ++reg) {
                    float g = accOG[m][n][reg];
                    float p = accOP[m][n][reg];
                    v[reg] = (bf16)(p * (1.f / (1.f + __expf(-g))));
                }
                *(bf16x4*)(ub + rr * 136 + dq * 32 + m * 16 + lh * 4) = v;
            }
        barrier_lds();   // B: ub visible; no vmcnt drain

        {
            float x[16];
            const bf16* ur = ub + r8 * 136 + q * 16;
            bf16x8 u0 = *(const bf16x8*)(ur);
            bf16x8 u1 = *(const bf16x8*)(ur + 8);
            #pragma unroll
            for (int e = 0; e < 4; ++e) {
                x[e]      = pA0[e] + (float)u0[e];
                x[4 + e]  = pA1[e] + (float)u0[4 + e];
                x[8 + e]  = pA2[e] + (float)u1[e];
                x[12 + e] = pA3[e] + (float)u1[4 + e];
            }
            float s1 = 0.f, s2 = 0.f;
            #pragma unroll
            for (int j = 0; j < 16; ++j) { s1 += x[j]; s2 += x[j] * x[j]; }
            s1 += __shfl_xor(s1, 1); s2 += __shfl_xor(s2, 1);
            s1 += __shfl_xor(s1, 2); s2 += __shfl_xor(s2, 2);
            s1 += __shfl_xor(s1, 4); s2 += __shfl_xor(s2, 4);
            float mean = s1 * (1.f / 128.f);
            float rstd = rsqrtf(s2 * (1.f / 128.f) - mean * mean + EPS);
            float* orow = out + (size_t)(row0 + r8) * 128 + q * 16;
            f32x4 o0, o1, o2, o3;
            #pragma unroll
            for (int e = 0; e < 4; ++e) {
                o0[e] = (x[e]      - mean) * rstd * lw0[e] + lb0[e];
                o1[e] = (x[4 + e]  - mean) * rstd * lw1[e] + lb1[e];
                o2[e] = (x[8 + e]  - mean) * rstd * lw2[e] + lb2[e];
                o3[e] = (x[12 + e] - mean) * rstd * lw3[e] + lb3[e];
            }
            *(f32x4*)(orow)      = o0;
            *(f32x4*)(orow + 4)  = o1;
            *(f32x4*)(orow + 8)  = o2;
            *(f32x4*)(orow + 12) = o3;
        }

        pA0 = pB0; pA1 = pB1; pA2 = pB2; pA3 = pB3;
        buf ^= 1;
    }
}

extern "C" void kernel_launch(void* const* d_in, const int* in_sizes, int n_in,
                              void* d_out, int out_size, void* d_ws, size_t ws_size,
                              hipStream_t stream) {
    const float* pair    = (const float*)d_in[0];
    const float* ln_in_w = (const float*)d_in[1];
    const float* ln_in_b = (const float*)d_in[2];
    const float* lp_w    = (const float*)d_in[3];
    const float* lp_b    = (const float*)d_in[4];
    const float* lg_w    = (const float*)d_in[5];
    const float* lg_b    = (const float*)d_in[6];
    const float* rp_w    = (const float*)d_in[7];
    const float* rp_b    = (const float*)d_in[8];
    const float* rg_w    = (const float*)d_in[9];
    const float* rg_b    = (const float*)d_in[10];
    const float* cn_w    = (const float*)d_in[11];
    const float* cn_b    = (const float*)d_in[12];
    const float* op_w    = (const float*)d_in[13];
    const float* op_b    = (const float*)d_in[14];
    const float* og_w    = (const float*)d_in[15];
    const float* og_b    = (const float*)d_in[16];
    const float* ln_out_w = (const float*)d_in[17];
    const float* ln_out_b = (const float*)d_in[18];

    const size_t HALF = (size_t)128 * NSQ * 2;   // 150,994,944 B
    char* ws = (char*)d_ws;
    bf16*  wbf     = (bf16*)ws;                   // 196608 B
    float* badj    = (float*)(ws + 196608);       // 5 x 128 fp32
    bf16*  right_t = (bf16*)(ws + 196608 + 4096);
    bf16*  tri_ln  = right_t;                     // reuse after K3
    bf16*  left_t  = (bf16*)d_out;
    bf16*  tri_t   = (bf16*)((char*)d_out + HALF);

    k_convert_w<<<dim3(64, 6), 256, 0, stream>>>(lp_w, lg_w, rp_w, rg_w, op_w, og_w,
                                                 ln_in_w, cn_w, wbf);
    k_bias<<<dim3(5), 128, 0, stream>>>(lp_w, lg_w, rp_w, rg_w, op_w,
                                        lp_b, lg_b, rp_b, rg_b, op_b,
                                        ln_in_b, cn_b, badj);
    k_ln_gate2<<<dim3(512), 512, 0, stream>>>(pair, wbf, badj, left_t, right_t);
    k_tri<<<dim3(1152), 512, 0, stream>>>(left_t, right_t, tri_t);
    k_cln<<<dim3(NSQ / 256), 256, 0, stream>>>(tri_t, tri_ln);
    k_final2<<<dim3(512), 512, 0, stream>>>(pair, tri_ln, wbf, badj + 512, og_b,
                                            ln_out_w, ln_out_b, (float*)d_out);
}

// Round 19
// 516.803 us; speedup vs baseline: 1.0515x; 1.0170x over previous
//
#include <hip/hip_runtime.h>

#define N 768
#define D 128
#define NSQ (N*N)
#define EPS 1e-5f

typedef __bf16 bf16;
typedef __bf16 bf16x4 __attribute__((ext_vector_type(4)));
typedef __bf16 bf16x8 __attribute__((ext_vector_type(8)));
typedef float f32x4 __attribute__((ext_vector_type(4)));

__device__ __forceinline__ void gld16(const void* g, void* l) {
    __builtin_amdgcn_global_load_lds(
        (const __attribute__((address_space(1))) unsigned int*)g,
        (__attribute__((address_space(3))) unsigned int*)l, 16, 0, 0);
}

// raw barrier: lgkm drain (LDS visibility) WITHOUT the vmcnt(0) store/DMA drain
__device__ __forceinline__ void barrier_lds() {
    asm volatile("s_waitcnt lgkmcnt(0)" ::: "memory");
    __builtin_amdgcn_s_barrier();
    __builtin_amdgcn_sched_barrier(0);
}

// fast sigmoid: v_rcp_f32 instead of the ~7-op exact divide sequence.
// ~1 ulp; result is immediately rounded to bf16 -> error << threshold.
__device__ __forceinline__ float fsigmoid(float g) {
    return __builtin_amdgcn_rcpf(1.f + __expf(-g));
}

// ---------------- K0a: convert weights fp32 -> bf16, LN/cn gamma folded -----
__global__ void k_convert_w(const float* __restrict__ lp, const float* __restrict__ lg,
                            const float* __restrict__ rp, const float* __restrict__ rg,
                            const float* __restrict__ op, const float* __restrict__ og,
                            const float* __restrict__ lnw, const float* __restrict__ cnw,
                            bf16* __restrict__ dst) {
    const float* srcs[6] = {lp, lg, rp, rg, op, og};
    int m = blockIdx.y;
    int i = blockIdx.x * 256 + threadIdx.x;   // 64 blocks x 256 = 16384
    float v = srcs[m][i];
    int k = i & 127;
    if (m < 4) v *= lnw[k];
    else if (m == 4) v *= cnw[k];
    dst[m * 16384 + i] = (bf16)v;
}

// ---------------- K0b: adjusted biases b' = b + W @ beta --------------------
__global__ void k_bias(const float* __restrict__ lp_w, const float* __restrict__ lg_w,
                       const float* __restrict__ rp_w, const float* __restrict__ rg_w,
                       const float* __restrict__ op_w,
                       const float* __restrict__ lp_b, const float* __restrict__ lg_b,
                       const float* __restrict__ rp_b, const float* __restrict__ rg_b,
                       const float* __restrict__ op_b,
                       const float* __restrict__ lnb, const float* __restrict__ cnb,
                       float* __restrict__ outb) {
    int m = blockIdx.x;       // 0..4
    int d = threadIdx.x;      // 0..127
    const float* W[5] = {lp_w, lg_w, rp_w, rg_w, op_w};
    const float* B[5] = {lp_b, lg_b, rp_b, rg_b, op_b};
    const float* beta = (m < 4) ? lnb : cnb;
    float s = B[m][d];
    for (int k = 0; k < 128; ++k) s += W[m][d * 128 + k] * beta[k];
    outb[m * 128 + d] = s;
}

// ---------------- K1v10: fused LN + 4 GEMMs + gates, fast sigmoid -----------
__global__ __launch_bounds__(512, 2) void k_ln_gate2(
    const float* __restrict__ pair, const bf16* __restrict__ wbf,
    const float* __restrict__ badj,
    bf16* __restrict__ left_t, bf16* __restrict__ right_t)
{
    __shared__ bf16 zt[2][64 * 128];   // 2 x 16 KB, xor-swizzled 16B chunks

    const int t = threadIdx.x;
    const int lane = t & 63, wid = t >> 6;
    const int side = wid >> 2, dq = wid & 3;
    const int lr = lane & 15, lh = lane >> 4;

    const bf16* wPsrc = wbf + (side ? 2 : 0) * 16384;
    const bf16* wGsrc = wbf + (side ? 3 : 1) * 16384;
    const float* bPp = badj + (side ? 2 : 0) * 128;
    const float* bGp = badj + (side ? 3 : 1) * 128;
    bf16* dst = side ? right_t : left_t;

    bf16x8 aP[4][2], aG[4][2];
    #pragma unroll
    for (int kk = 0; kk < 4; ++kk)
        #pragma unroll
        for (int m = 0; m < 2; ++m) {
            int rd = dq * 32 + m * 16 + lr;
            aP[kk][m] = *(const bf16x8*)(wPsrc + rd * 128 + (kk * 4 + lh) * 8);
            aG[kk][m] = *(const bf16x8*)(wGsrc + rd * 128 + (kk * 4 + lh) * 8);
        }
    float bP[2], bG[2];
    #pragma unroll
    for (int m = 0; m < 2; ++m) {
        bP[m] = bPp[dq * 32 + m * 16 + lr];
        bG[m] = bGp[dq * 32 + m * 16 + lr];
    }

    const int r8 = t >> 3, q = t & 7;

    const int bid = blockIdx.x, gstride = gridDim.x;
    const int NT = NSQ / 64;

    f32x4 p0, p1, p2, p3;

    auto ln_to = [&](int b) {
        float x[16];
        #pragma unroll
        for (int e = 0; e < 4; ++e) {
            x[e] = p0[e]; x[4 + e] = p1[e]; x[8 + e] = p2[e]; x[12 + e] = p3[e];
        }
        float s1 = 0.f, s2 = 0.f;
        #pragma unroll
        for (int j = 0; j < 16; ++j) { s1 += x[j]; s2 += x[j] * x[j]; }
        s1 += __shfl_xor(s1, 1); s2 += __shfl_xor(s2, 1);
        s1 += __shfl_xor(s1, 2); s2 += __shfl_xor(s2, 2);
        s1 += __shfl_xor(s1, 4); s2 += __shfl_xor(s2, 4);
        float mean = s1 * (1.f / 128.f);
        float rstd = rsqrtf(s2 * (1.f / 128.f) - mean * mean + EPS);
        bf16x8 pk0, pk1;
        #pragma unroll
        for (int e = 0; e < 4; ++e) {
            pk0[e]     = (bf16)((x[e]      - mean) * rstd);
            pk0[4 + e] = (bf16)((x[4 + e]  - mean) * rstd);
            pk1[e]     = (bf16)((x[8 + e]  - mean) * rstd);
            pk1[4 + e] = (bf16)((x[12 + e] - mean) * rstd);
        }
        char* zb = (char*)&zt[b][0];
        *(bf16x8*)(zb + r8 * 256 + ((q * 2)     ^ (r8 & 7)) * 16) = pk0;
        *(bf16x8*)(zb + r8 * 256 + ((q * 2 + 1) ^ (r8 & 7)) * 16) = pk1;
    };
    auto load_regs = [&](int tile) {
        const float* prow = pair + (size_t)(tile * 64 + r8) * 128 + q * 16;
        p0 = *(const f32x4*)(prow);
        p1 = *(const f32x4*)(prow + 4);
        p2 = *(const f32x4*)(prow + 8);
        p3 = *(const f32x4*)(prow + 12);
    };

    load_regs(bid);
    ln_to(0);
    if (bid + gstride < NT) load_regs(bid + gstride);
    barrier_lds();

    int buf = 0;
    for (int tile = bid; tile < NT; tile += gstride) {
        const int row0 = tile * 64;
        const int nt = tile + gstride;

        if (nt < NT) ln_to(buf ^ 1);
        if (nt + gstride < NT) load_regs(nt + gstride);

        // bias pre-loaded into accumulators (C-in accumulates)
        f32x4 accP[2][4], accG[2][4];
        #pragma unroll
        for (int m = 0; m < 2; ++m)
            #pragma unroll
            for (int n = 0; n < 4; ++n) {
                accP[m][n] = f32x4{bP[m], bP[m], bP[m], bP[m]};
                accG[m][n] = f32x4{bG[m], bG[m], bG[m], bG[m]};
            }
        const char* zb = (const char*)&zt[buf][0];
        #pragma unroll
        for (int kk = 0; kk < 4; ++kk) {
            bf16x8 bz[4];
            #pragma unroll
            for (int n = 0; n < 4; ++n) {
                int rz = n * 16 + lr;
                bz[n] = *(const bf16x8*)(zb + rz * 256 + (((kk * 4 + lh)) ^ (rz & 7)) * 16);
            }
            #pragma unroll
            for (int m = 0; m < 2; ++m)
                #pragma unroll
                for (int n = 0; n < 4; ++n) {
                    accP[m][n] = __builtin_amdgcn_mfma_f32_16x16x32_bf16(bz[n], aP[kk][m], accP[m][n], 0, 0, 0);
                    accG[m][n] = __builtin_amdgcn_mfma_f32_16x16x32_bf16(bz[n], aG[kk][m], accG[m][n], 0, 0, 0);
                }
        }

        #pragma unroll
        for (int m = 0; m < 2; ++m) {
            const int d = dq * 32 + m * 16 + lr;
            bf16* drow = dst + (size_t)d * NSQ + row0 + lh * 4;
            #pragma unroll
            for (int n = 0; n < 4; ++n) {
                bf16x4 pk;
                #pragma unroll
                for (int reg = 0; reg < 4; ++reg)
                    pk[reg] = (bf16)(accP[m][n][reg] * fsigmoid(accG[m][n][reg]));
                *(bf16x4*)(drow + n * 16) = pk;
            }
        }
        barrier_lds();
        buf ^= 1;
    }
}

// ---------------- K3v10: 256^2, counted-vmcnt, 2 phases per K-tile ----------
__global__ __launch_bounds__(512, 2) void k_tri(
    const bf16* __restrict__ left_t, const bf16* __restrict__ right_t, bf16* __restrict__ tri_t)
{
    __shared__ bf16 at[2][256 * 64];   // 2 x 32 KB
    __shared__ bf16 bt[2][256 * 64];   // 2 x 32 KB
    const int t = threadIdx.x;
    const int b = blockIdx.x;
    const int xcd = b & 7;
    const int s = b >> 3;              // 0..143
    const int d = xcd * 16 + s / 9;
    const int tile = s % 9;
    const int ti = tile / 3, tj = tile % 3;
    const bf16* A = left_t + (size_t)d * NSQ;
    const bf16* B = right_t + (size_t)d * NSQ;
    const int i0 = ti * 256, j0 = tj * 256;

    const int lane = t & 63, wid = t >> 6;
    const int wr = wid >> 2, wc = wid & 3;
    const int lr = lane & 15, lh = lane >> 4;

    const bf16* SRC = (wid < 4) ? A : B;
    const int srcbase = (wid < 4) ? i0 : j0;
    const int w4 = wid & 3;
    auto stage4 = [&](int bf, int kt, int half) {
        char* dstb = (wid < 4) ? (char*)at[bf] : (char*)bt[bf];
        #pragma unroll
        for (int i2 = 0; i2 < 4; ++i2) {
            int i = half * 4 + i2;
            int rl = w4 * 64 + i * 8 + (lane >> 3);
            int lc = (lane & 7) ^ (rl & 7);
            gld16(SRC + (size_t)(srcbase + rl) * 768 + kt * 64 + lc * 8,
                  dstb + rl * 128 + (lane & 7) * 16);
        }
    };

    f32x4 acc[8][4] = {};

    stage4(0, 0, 0);
    stage4(0, 0, 1);
    asm volatile("s_waitcnt vmcnt(0)" ::: "memory");
    __builtin_amdgcn_s_barrier();
    __builtin_amdgcn_sched_barrier(0);

    for (int kt = 0; kt < 12; ++kt) {
        const int bf = kt & 1;
        const char* ab = (const char*)at[bf];
        const char* bb = (const char*)bt[bf];
        #pragma unroll
        for (int kk = 0; kk < 2; ++kk) {
            if (kk == 0) {
                if (kt < 11) {
                    stage4(bf ^ 1, kt + 1, 0);
                    asm volatile("s_waitcnt vmcnt(4)" ::: "memory");
                } else {
                    asm volatile("s_waitcnt vmcnt(0)" ::: "memory");
                }
                __builtin_amdgcn_s_barrier();
                __builtin_amdgcn_sched_barrier(0);
            } else {
                if (kt < 11) stage4(bf ^ 1, kt + 1, 1);
            }
            bf16x8 bff[4], af[8];
            #pragma unroll
            for (int n = 0; n < 4; ++n) {
                int r = wc * 64 + n * 16 + lr;
                bff[n] = *(const bf16x8*)(bb + r * 128 + (((kk * 4 + lh)) ^ (r & 7)) * 16);
            }
            #pragma unroll
            for (int mi = 0; mi < 8; ++mi) {
                int r = wr * 128 + mi * 16 + lr;
                af[mi] = *(const bf16x8*)(ab + r * 128 + (((kk * 4 + lh)) ^ (r & 7)) * 16);
            }
            asm volatile("s_waitcnt lgkmcnt(0)" ::: "memory");
            __builtin_amdgcn_sched_barrier(0);
            __builtin_amdgcn_s_setprio(1);
            #pragma unroll
            for (int mi = 0; mi < 8; ++mi)
                #pragma unroll
                for (int n = 0; n < 4; ++n)
                    acc[mi][n] = __builtin_amdgcn_mfma_f32_16x16x32_bf16(
                        bff[n], af[mi], acc[mi][n], 0, 0, 0);
            __builtin_amdgcn_s_setprio(0);
        }
        __builtin_amdgcn_s_barrier();
        __builtin_amdgcn_sched_barrier(0);
    }

    bf16* C = tri_t + (size_t)d * NSQ;
    #pragma unroll
    for (int m = 0; m < 8; ++m) {
        const int ri = i0 + wr * 128 + m * 16 + lr;
        bf16* crow = C + (size_t)ri * 768 + j0 + wc * 64 + lh * 4;
        #pragma unroll
        for (int n = 0; n < 4; ++n) {
            bf16x4 pk;
            #pragma unroll
            for (int reg = 0; reg < 4; ++reg)
                pk[reg] = (bf16)acc[m][n][reg];
            *(bf16x4*)(crow + n * 16) = pk;
        }
    }
}

// ---------------- K4v3: LN over d (gamma/beta folded downstream) ------------
__global__ __launch_bounds__(256, 2) void k_cln(
    const bf16* __restrict__ tri_t, bf16* __restrict__ tri_ln)
{
    __shared__ bf16 tile[256 * 128];   // 64 KB raw values
    __shared__ float mrs[256][2];      // mean, rstd
    const int t = threadIdx.x;
    const size_t ij = (size_t)blockIdx.x * 256 + t;
    float s1 = 0.f, s2 = 0.f;
    for (int dc = 0; dc < 16; ++dc) {
        bf16x8 pk;
        #pragma unroll
        for (int e = 0; e < 8; ++e) {
            int dd = dc * 8 + e;
            bf16 raw = tri_t[(size_t)dd * NSQ + ij];
            float v = (float)raw;
            s1 += v; s2 += v * v;
            pk[e] = raw;
        }
        *(bf16x8*)((char*)tile + t * 256 + (dc ^ (t & 7)) * 16) = pk;
    }
    float mean = s1 * (1.f / 128.f);
    float rstd = rsqrtf(s2 * (1.f / 128.f) - mean * mean + EPS);
    mrs[t][0] = mean; mrs[t][1] = rstd;
    __syncthreads();
    const size_t ij0 = (size_t)blockIdx.x * 256;
    #pragma unroll
    for (int c = 0; c < 16; ++c) {
        int sl = c * 256 + t;
        int rl = sl >> 4, cp = sl & 15, cl = cp ^ (rl & 7);
        bf16x8 raw = *(const bf16x8*)((const char*)tile + rl * 256 + cp * 16);
        float m = mrs[rl][0], r = mrs[rl][1];
        bf16x8 o;
        #pragma unroll
        for (int e = 0; e < 8; ++e)
            o[e] = (bf16)(((float)raw[e] - m) * r);
        *(bf16x8*)(tri_ln + (ij0 + rl) * 128 + cl * 8) = o;
    }
}

// ---------------- K5v10: fused out-gate + residual + final LN ---------------
__global__ __launch_bounds__(512, 2) void k_final2(
    const float* __restrict__ pair, const bf16* __restrict__ tri_ln,
    const bf16* __restrict__ wbf,
    const float* __restrict__ opb_adj, const float* __restrict__ og_b,
    const float* __restrict__ lnow, const float* __restrict__ lnob,
    float* __restrict__ out)
{
    __shared__ bf16 zt[64 * 128];       // raw pair bf16, swizzled      16 KB
    __shared__ bf16 tt[2][64 * 128];    // tri_ln, swizzled, dbuf       32 KB
    __shared__ bf16 ub[64 * 136];       // gated output exchange        17 KB

    const int t = threadIdx.x;
    const int lane = t & 63, wid = t >> 6;
    const int dq = wid & 3, wh = wid >> 2;
    const int lr = lane & 15, lh = lane >> 4;

    const bf16* opsrc = wbf + 4 * 16384;
    const bf16* ogsrc = wbf + 5 * 16384;

    bf16x8 aOG[4][2], aOP[4][2];
    #pragma unroll
    for (int kk = 0; kk < 4; ++kk)
        #pragma unroll
        for (int m = 0; m < 2; ++m) {
            int rd = dq * 32 + m * 16 + lr;
            aOG[kk][m] = *(const bf16x8*)(ogsrc + rd * 128 + (kk * 4 + lh) * 8);
            aOP[kk][m] = *(const bf16x8*)(opsrc + rd * 128 + (kk * 4 + lh) * 8);
        }
    f32x4 vbOG[2], vbOP[2];
    #pragma unroll
    for (int m = 0; m < 2; ++m) {
        vbOG[m] = *(const f32x4*)(og_b + dq * 32 + m * 16 + lh * 4);
        vbOP[m] = *(const f32x4*)(opb_adj + dq * 32 + m * 16 + lh * 4);
    }

    const int r8 = t >> 3, q = t & 7;
    f32x4 lw0 = *(const f32x4*)(lnow + q * 16);
    f32x4 lw1 = *(const f32x4*)(lnow + q * 16 + 4);
    f32x4 lw2 = *(const f32x4*)(lnow + q * 16 + 8);
    f32x4 lw3 = *(const f32x4*)(lnow + q * 16 + 12);
    f32x4 lb0 = *(const f32x4*)(lnob + q * 16);
    f32x4 lb1 = *(const f32x4*)(lnob + q * 16 + 4);
    f32x4 lb2 = *(const f32x4*)(lnob + q * 16 + 8);
    f32x4 lb3 = *(const f32x4*)(lnob + q * 16 + 12);

    const int bid = blockIdx.x, gstride = gridDim.x;

    auto stage_tt = [&](int buf, int tile) {
        const int row0 = tile * 64;
        #pragma unroll
        for (int c = 0; c < 2; ++c) {
            int s = c * 512 + t;                 // 1024 slots of 16B
            int r = s >> 4, cp = s & 15, cl = cp ^ (r & 7);
            gld16(tri_ln + (size_t)(row0 + r) * 128 + cl * 8, (char*)tt[buf] + s * 16);
        }
    };

    stage_tt(0, bid);
    f32x4 pA0, pA1, pA2, pA3;
    {
        const float* prow = pair + (size_t)(bid * 64 + r8) * 128 + q * 16;
        pA0 = *(const f32x4*)(prow);
        pA1 = *(const f32x4*)(prow + 4);
        pA2 = *(const f32x4*)(prow + 8);
        pA3 = *(const f32x4*)(prow + 12);
    }

    int buf = 0;
    for (int tile = bid; tile < NSQ / 64; tile += gstride) {
        const int row0 = tile * 64;

        {
            bf16x8 pk0, pk1;
            #pragma unroll
            for (int e = 0; e < 4; ++e) {
                pk0[e]     = (bf16)pA0[e];
                pk0[4 + e] = (bf16)pA1[e];
                pk1[e]     = (bf16)pA2[e];
                pk1[4 + e] = (bf16)pA3[e];
            }
            char* zb = (char*)zt;
            *(bf16x8*)(zb + r8 * 256 + ((q * 2)     ^ (r8 & 7)) * 16) = pk0;
            *(bf16x8*)(zb + r8 * 256 + ((q * 2 + 1) ^ (r8 & 7)) * 16) = pk1;
        }
        barrier_lds();   // A: zt + tt[buf] ready

        const int nt = tile + gstride;
        if (nt < NSQ / 64) stage_tt(buf ^ 1, nt);

        f32x4 pB0 = pA0, pB1 = pA1, pB2 = pA2, pB3 = pA3;
        if (nt < NSQ / 64) {
            const float* prow = pair + (size_t)(nt * 64 + r8) * 128 + q * 16;
            pB0 = *(const f32x4*)(prow);
            pB1 = *(const f32x4*)(prow + 4);
            pB2 = *(const f32x4*)(prow + 8);
            pB3 = *(const f32x4*)(prow + 12);
        }

        f32x4 accOG[2][2], accOP[2][2];
        #pragma unroll
        for (int m = 0; m < 2; ++m)
            #pragma unroll
            for (int n = 0; n < 2; ++n) {
                accOG[m][n] = vbOG[m];
                accOP[m][n] = vbOP[m];
            }
        const char* zb = (const char*)zt;
        const char* tb = (const char*)tt[buf];
        #pragma unroll
        for (int kk = 0; kk < 4; ++kk) {
            bf16x8 bzp[2], bzt[2];
            #pragma unroll
            for (int n = 0; n < 2; ++n) {
                int rz = wh * 32 + n * 16 + lr;
                int phys = (kk * 4 + lh) ^ (rz & 7);
                bzp[n] = *(const bf16x8*)(zb + rz * 256 + phys * 16);
                bzt[n] = *(const bf16x8*)(tb + rz * 256 + phys * 16);
            }
            #pragma unroll
            for (int m = 0; m < 2; ++m)
                #pragma unroll
                for (int n = 0; n < 2; ++n) {
                    accOG[m][n] = __builtin_amdgcn_mfma_f32_16x16x32_bf16(aOG[kk][m], bzp[n], accOG[m][n], 0, 0, 0);
                    accOP[m][n] = __builtin_amdgcn_mfma_f32_16x16x32_bf16(aOP[kk][m], bzt[n], accOP[m][n], 0, 0, 0);
                }
        }

        #pragma unroll
        for (int m = 0; m < 2; ++m)
            #pragma unroll
            for (int n = 0; n < 2; ++n) {
                int rr = wh * 32 + n * 16 + lr;
                bf16x4 v;
                #pragma unroll
                for (int reg = 0; reg < 4; ++reg)
                    v[reg] = (bf16)(accOP[m][n][reg] * fsigmoid(accOG[m][n][reg]));
                *(bf16x4*)(ub + rr * 136 + dq * 32 + m * 16 + lh * 4) = v;
            }
        barrier_lds();   // B: ub visible; no vmcnt drain

        {
            float x[16];
            const bf16* ur = ub + r8 * 136 + q * 16;
            bf16x8 u0 = *(const bf16x8*)(ur);
            bf16x8 u1 = *(const bf16x8*)(ur + 8);
            #pragma unroll
            for (int e = 0; e < 4; ++e) {
                x[e]      = pA0[e] + (float)u0[e];
                x[4 + e]  = pA1[e] + (float)u0[4 + e];
                x[8 + e]  = pA2[e] + (float)u1[e];
                x[12 + e] = pA3[e] + (float)u1[4 + e];
            }
            float s1 = 0.f, s2 = 0.f;
            #pragma unroll
            for (int j = 0; j < 16; ++j) { s1 += x[j]; s2 += x[j] * x[j]; }
            s1 += __shfl_xor(s1, 1); s2 += __shfl_xor(s2, 1);
            s1 += __shfl_xor(s1, 2); s2 += __shfl_xor(s2, 2);
            s1 += __shfl_xor(s1, 4); s2 += __shfl_xor(s2, 4);
            float mean = s1 * (1.f / 128.f);
            float rstd = rsqrtf(s2 * (1.f / 128.f) - mean * mean + EPS);
            float* orow = out + (size_t)(row0 + r8) * 128 + q * 16;
            f32x4 o0, o1, o2, o3;
            #pragma unroll
            for (int e = 0; e < 4; ++e) {
                o0[e] = (x[e]      - mean) * rstd * lw0[e] + lb0[e];
                o1[e] = (x[4 + e]  - mean) * rstd * lw1[e] + lb1[e];
                o2[e] = (x[8 + e]  - mean) * rstd * lw2[e] + lb2[e];
                o3[e] = (x[12 + e] - mean) * rstd * lw3[e] + lb3[e];
            }
            *(f32x4*)(orow)      = o0;
            *(f32x4*)(orow + 4)  = o1;
            *(f32x4*)(orow + 8)  = o2;
            *(f32x4*)(orow + 12) = o3;
        }

        pA0 = pB0; pA1 = pB1; pA2 = pB2; pA3 = pB3;
        buf ^= 1;
    }
}

extern "C" void kernel_launch(void* const* d_in, const int* in_sizes, int n_in,
                              void* d_out, int out_size, void* d_ws, size_t ws_size,
                              hipStream_t stream) {
    const float* pair    = (const float*)d_in[0];
    const float* ln_in_w = (const float*)d_in[1];
    const float* ln_in_b = (const float*)d_in[2];
    const float* lp_w    = (const float*)d_in[3];
    const float* lp_b    = (const float*)d_in[4];
    const float* lg_w    = (const float*)d_in[5];
    const float* lg_b    = (const float*)d_in[6];
    const float* rp_w    = (const float*)d_in[7];
    const float* rp_b    = (const float*)d_in[8];
    const float* rg_w    = (const float*)d_in[9];
    const float* rg_b    = (const float*)d_in[10];
    const float* cn_w    = (const float*)d_in[11];
    const float* cn_b    = (const float*)d_in[12];
    const float* op_w    = (const float*)d_in[13];
    const float* op_b    = (const float*)d_in[14];
    const float* og_w    = (const float*)d_in[15];
    const float* og_b    = (const float*)d_in[16];
    const float* ln_out_w = (const float*)d_in[17];
    const float* ln_out_b = (const float*)d_in[18];

    const size_t HALF = (size_t)128 * NSQ * 2;   // 150,994,944 B
    char* ws = (char*)d_ws;
    bf16*  wbf     = (bf16*)ws;                   // 196608 B
    float* badj    = (float*)(ws + 196608);       // 5 x 128 fp32
    bf16*  right_t = (bf16*)(ws + 196608 + 4096);
    bf16*  tri_ln  = right_t;                     // reuse after K3
    bf16*  left_t  = (bf16*)d_out;
    bf16*  tri_t   = (bf16*)((char*)d_out + HALF);

    k_convert_w<<<dim3(64, 6), 256, 0, stream>>>(lp_w, lg_w, rp_w, rg_w, op_w, og_w,
                                                 ln_in_w, cn_w, wbf);
    k_bias<<<dim3(5), 128, 0, stream>>>(lp_w, lg_w, rp_w, rg_w, op_w,
                                        lp_b, lg_b, rp_b, rg_b, op_b,
                                        ln_in_b, cn_b, badj);
    k_ln_gate2<<<dim3(512), 512, 0, stream>>>(pair, wbf, badj, left_t, right_t);
    k_tri<<<dim3(1152), 512, 0, stream>>>(left_t, right_t, tri_t);
    k_cln<<<dim3(NSQ / 256), 256, 0, stream>>>(tri_t, tri_ln);
    k_final2<<<dim3(512), 512, 0, stream>>>(pair, tri_ln, wbf, badj + 512, og_b,
                                            ln_out_w, ln_out_b, (float*)d_out);
}